// Round 4
// baseline (1056.454 us; speedup 1.0000x reference)
//
#include <hip/hip_runtime.h>
#include <cmath>

// ---------------------------------------------------------------------------
// EquivariantCorrectionHead — round 4: round-3 structure, C222 sign FLIPPED.
// One full wave (64 lanes) per batch element; lanes 32..63 mirror 0..31.
// All cross-lane communication via __shfl. fp32 everywhere.
// C222 sign: the exact tensor has a 7-way max-|.| tie (+-2/sqrt6); the
// reference breaks it via np.argmax on SVD noise. Rounds 1-3 (C[0,0,2]>0)
// all failed with identical absmax=721 across disjoint implementations ->
// flip to the opposite convention (C[2,2,2]>0).
// ---------------------------------------------------------------------------

#define OFF_C     0        // 125
#define OFF_W000  128      // 32 x 136 (sym upper-tri of 16x16, c0 folded)
#define OFF_W110  4480     // 32 x 45  (sym upper-tri of 9x9, c0/sqrt5 folded)
#define OFF_WC    5920     // 32 x 144 (w011[a,m,w]+w101[m,a,w], c2/sqrt5)
#define OFF_W111  10528    // 32 x 45  (sym, c2 folded)
#define OFF_V110  11968    // 32 x 32
#define OFF_MR    12992    // 32 x 32  (d/sqrt5 * (v010[u,w]+v100[w,u]))
#define WS_WORDS  14016

__device__ __align__(16) float g_ws[WS_WORDS];

__host__ __device__ inline void tri_uv(int p, int n, int& u, int& v) {
  int base = 0;
  for (int x = 0; x < n; x++) {
    int c = n - x;
    if (p < base + c) { u = x; v = x + (p - base); return; }
    base += c;
  }
  u = n - 1; v = n - 1;
}

static __device__ __forceinline__ double trE3(const double A[3][3], const double B[3][3],
                                              const double C[3][3]) {
  double t = 0.0;
  for (int r = 0; r < 3; r++)
    for (int c = 0; c < 3; c++) {
      double ab = 0.0;
      for (int m = 0; m < 3; m++) ab += A[r][m] * B[m][c];
      t += ab * C[c][r];
    }
  return t;
}

// ---------------------------------------------------------------------------
// Setup: C222 analytic (every block, idempotent) + weight preprocessing
// ---------------------------------------------------------------------------
__global__ void ech_setup(const float* __restrict__ w000, const float* __restrict__ w110,
                          const float* __restrict__ w011, const float* __restrict__ w101,
                          const float* __restrict__ w111, const float* __restrict__ v010,
                          const float* __restrict__ v100, const float* __restrict__ v110) {
  __shared__ double Tsh[125];
  {
    const double s2i = 0.7071067811865475244;
    const double s6i = 0.4082482904638630164;
    double E[5][3][3] = {
      {{0, s2i, 0}, {s2i, 0, 0}, {0, 0, 0}},
      {{0, 0, 0}, {0, 0, s2i}, {0, s2i, 0}},
      {{-s6i, 0, 0}, {0, -s6i, 0}, {0, 0, 2.0 * s6i}},
      {{0, 0, s2i}, {0, 0, 0}, {s2i, 0, 0}},
      {{s2i, 0, 0}, {0, -s2i, 0}, {0, 0, 0}}
    };
    int f = threadIdx.x;
    if (f < 125) {
      int i = f / 25, j = (f / 5) % 5, k = f % 5;
      Tsh[f] = trE3(E[i], E[j], E[k]) + trE3(E[i], E[k], E[j]);
    }
    __syncthreads();
    if (f < 125) {
      double nrm = 0.0;
      for (int q = 0; q < 125; q++) nrm += Tsh[q] * Tsh[q];
      nrm = sqrt(nrm);
      int am = 0; double mx = fabs(Tsh[0]);
      for (int q = 1; q < 125; q++) { double v = fabs(Tsh[q]); if (v > mx) { mx = v; am = q; } }
      double sgn = (Tsh[am] < 0.0) ? -1.0 : 1.0;
      // SIGN FLIP vs rounds 1-3 (see header comment):
      g_ws[OFF_C + f] = (float)(-sgn * Tsh[f] / nrm);
    }
  }

  const float c0   = 1.0f / sqrtf(337.0f);
  const float inv5 = 0.44721359549995794f;
  const float c2   = sqrtf(5.0f / 369.0f);
  const float dcon = sqrtf(5.0f / 3072.0f);
  int gid = blockIdx.x * blockDim.x + threadIdx.x;
  int gs  = gridDim.x * blockDim.x;

  // w000 symmetrized upper-tri, c0 folded: [w][p] p<136
  for (int idx = gid; idx < 32 * 136; idx += gs) {
    int w = idx / 136, p = idx % 136; int u, v; tri_uv(p, 16, u, v);
    g_ws[OFF_W000 + w * 136 + p] =
        c0 * (w000[(u * 16 + v) * 32 + w] + (u != v ? w000[(v * 16 + u) * 32 + w] : 0.0f));
  }
  // w110 symmetrized, c0/sqrt5 folded: [w][p] p<45
  for (int idx = gid; idx < 32 * 45; idx += gs) {
    int w = idx / 45, p = idx % 45; int u, v; tri_uv(p, 9, u, v);
    g_ws[OFF_W110 + w * 45 + p] =
        c0 * inv5 * (w110[(u * 9 + v) * 32 + w] + (u != v ? w110[(v * 9 + u) * 32 + w] : 0.0f));
  }
  // wc[w][a*9+m] = c2/sqrt5 * (w011[a,m,w] + w101[m,a,w]),  a<16 scalar, m<9
  for (int idx = gid; idx < 32 * 144; idx += gs) {
    int w = idx / 144, uv = idx % 144, a = uv / 9, m = uv % 9;
    g_ws[OFF_WC + w * 144 + uv] =
        c2 * inv5 * (w011[(a * 9 + m) * 32 + w] + w101[(m * 16 + a) * 32 + w]);
  }
  // w111 symmetrized, c2 folded: [w][p]
  for (int idx = gid; idx < 32 * 45; idx += gs) {
    int w = idx / 45, p = idx % 45; int u, v; tri_uv(p, 9, u, v);
    g_ws[OFF_W111 + w * 45 + p] =
        c2 * (w111[(u * 9 + v) * 32 + w] + (u != v ? w111[(v * 9 + u) * 32 + w] : 0.0f));
  }
  // v110: [u][v]
  for (int idx = gid; idx < 1024; idx += gs) {
    int u = idx / 32, v = idx % 32;
    g_ws[OFF_V110 + u * 32 + v] = v110[u * 32 + v];
  }
  // Mr[w][u] = d/sqrt5 * (v010[u,w] + v100[w,u])
  for (int idx = gid; idx < 1024; idx += gs) {
    int w = idx / 32, u = idx % 32;
    g_ws[OFF_MR + w * 32 + u] = dcon * inv5 * (v010[u * 32 + w] + v100[w * 32 + u]);
  }
}

// ---------------------------------------------------------------------------
// Main kernel: one wave per element
// ---------------------------------------------------------------------------
__global__ void __launch_bounds__(256)
ech_main(const float* __restrict__ sc, const float* __restrict__ t2s,
         float* __restrict__ out) {
  __shared__ float tLDS[4][48];

  const int tid   = threadIdx.x;
  const int lane  = tid & 63;
  const int wslot = tid >> 6;
  const int b     = blockIdx.x * 4 + wslot;
  const int w     = lane & 31;           // hidden index (upper half mirrors lower)

  const float* trow = t2s + (size_t)b * 200;
  const float* srow = sc + (size_t)b * 16;

  // ---- scalars (uniform across wave) ----
  float s[16];
  #pragma unroll
  for (int i = 0; i < 16; i++) s[i] = srow[i];

  // ---- build t (9x5: 8 selected rows + kernel-sum row) into LDS ----
  if (lane < 45) {
    int r = lane / 5, c = lane % 5;
    float val;
    if (r < 8) {
      int l2r = (r == 0) ? 0 : (r == 1) ? 1 : (r == 2) ? 2 : (r == 3) ? 4
              : (r == 4) ? 24 : (r == 5) ? 26 : (r == 6) ? 35 : 38;
      val = trow[l2r * 5 + c];
    } else {
      val = 0.0f;
      for (int k = 0; k < 40; k++) val += trow[k * 5 + c];
    }
    tLDS[wslot][r * 5 + c] = val;
  }
  __syncthreads();

  // ---- own pair (lane p < 45): tt and qT ----
  int pp = (lane < 45) ? lane : 44;
  int pu, pv; tri_uv(pp, 9, pu, pv);
  float tu[5], tv[5];
  #pragma unroll
  for (int i = 0; i < 5; i++) { tu[i] = tLDS[wslot][pu * 5 + i]; tv[i] = tLDS[wslot][pv * 5 + i]; }

  float ttp = tu[0]*tv[0] + tu[1]*tv[1] + tu[2]*tv[2] + tu[3]*tv[3] + tu[4]*tv[4];

  float qk[5] = {0, 0, 0, 0, 0};
  {
    const float* C = g_ws + OFF_C;
    #pragma unroll
    for (int i = 0; i < 5; i++)
      #pragma unroll
      for (int j = 0; j < 5; j++) {
        float pr = tu[i] * tv[j];
        #pragma unroll
        for (int k = 0; k < 5; k++) qk[k] = fmaf(C[(i * 5 + j) * 5 + k], pr, qk[k]);
      }
  }

  // ---- h0[w] ----
  float h0 = 0.0f;
  {
    const float* w000r = g_ws + OFF_W000 + w * 136;
    int p = 0;
    #pragma unroll
    for (int u = 0; u < 16; u++)
      #pragma unroll
      for (int v = u; v < 16; v++) { h0 = fmaf(w000r[p], s[u] * s[v], h0); p++; }
    const float* w110r = g_ws + OFF_W110 + w * 45;
    #pragma unroll
    for (int p2 = 0; p2 < 45; p2++) h0 = fmaf(w110r[p2], __shfl(ttp, p2), h0);
  }

  // ---- h2[w][k]: s-t merged path ----
  float h2[5] = {0, 0, 0, 0, 0};
  {
    const float* wcr = g_ws + OFF_WC + w * 144;
    float Cvv[9] = {0, 0, 0, 0, 0, 0, 0, 0, 0};
    #pragma unroll
    for (int u = 0; u < 16; u++) {
      float su = s[u];
      #pragma unroll
      for (int v = 0; v < 9; v++) Cvv[v] = fmaf(wcr[u * 9 + v], su, Cvv[v]);
    }
    #pragma unroll
    for (int v = 0; v < 9; v++) {
      float cv = Cvv[v];
      #pragma unroll
      for (int k = 0; k < 5; k++) h2[k] = fmaf(cv, tLDS[wslot][v * 5 + k], h2[k]);
    }
  }
  // ---- h2: w111 x u2 path (qT gathered by shfl) ----
  {
    const float* w111r = g_ws + OFF_W111 + w * 45;
    #pragma unroll
    for (int p2 = 0; p2 < 45; p2++) {
      float wv = w111r[p2];
      #pragma unroll
      for (int k = 0; k < 5; k++) h2[k] = fmaf(wv, __shfl(qk[k], p2), h2[k]);
    }
  }

  // ---- a[j] = sum_v v110[w,v] h2[v,j] (h2 by shfl from lanes 0..31) ----
  float a[5] = {0, 0, 0, 0, 0};
  {
    const float* vr = g_ws + OFF_V110 + w * 32;
    #pragma unroll
    for (int v = 0; v < 32; v++) {
      float wv = vr[v];
      #pragma unroll
      for (int j = 0; j < 5; j++) a[j] = fmaf(wv, __shfl(h2[j], v), a[j]);
    }
  }

  // ---- g = sum_u Mr[w,u] h0[u] ----
  float g = 0.0f;
  {
    const float* mr = g_ws + OFF_MR + w * 32;
    #pragma unroll
    for (int u = 0; u < 32; u++) g = fmaf(mr[u], __shfl(h0, u), g);
  }

  // ---- yv[k] = sum_ij C[i,j,k] h2[i] a[j] ----
  float yv[5] = {0, 0, 0, 0, 0};
  {
    const float* C = g_ws + OFF_C;
    #pragma unroll
    for (int i = 0; i < 5; i++)
      #pragma unroll
      for (int j = 0; j < 5; j++) {
        float pr = h2[i] * a[j];
        #pragma unroll
        for (int k = 0; k < 5; k++) yv[k] = fmaf(C[(i * 5 + j) * 5 + k], pr, yv[k]);
      }
  }

  const float DCONST = sqrtf(5.0f / 3072.0f);
  float z[5];
  #pragma unroll
  for (int k = 0; k < 5; k++) z[k] = fmaf(DCONST, yv[k], g * h2[k]);

  // ---- reduce over w (64 lanes hold each w twice -> halve) ----
  #pragma unroll
  for (int k = 0; k < 5; k++) {
    float v = z[k];
    v += __shfl_xor(v, 1);
    v += __shfl_xor(v, 2);
    v += __shfl_xor(v, 4);
    v += __shfl_xor(v, 8);
    v += __shfl_xor(v, 16);
    v += __shfl_xor(v, 32);
    z[k] = v * 0.5f;
  }
  if (lane < 5) {
    float val = (lane == 0) ? z[0] : (lane == 1) ? z[1] : (lane == 2) ? z[2]
              : (lane == 3) ? z[3] : z[4];
    out[(size_t)b * 5 + lane] = val;
  }
}

// ---------------------------------------------------------------------------
extern "C" void kernel_launch(void* const* d_in, const int* in_sizes, int n_in,
                              void* d_out, int out_size, void* d_ws, size_t ws_size,
                              hipStream_t stream) {
  (void)n_in; (void)out_size; (void)d_ws; (void)ws_size;

  ech_setup<<<64, 256, 0, stream>>>(
      (const float*)d_in[2], (const float*)d_in[3], (const float*)d_in[4],
      (const float*)d_in[5], (const float*)d_in[6], (const float*)d_in[7],
      (const float*)d_in[8], (const float*)d_in[9]);

  const int B = in_sizes[0] / 16;
  ech_main<<<B / 4, 256, 0, stream>>>(
      (const float*)d_in[0], (const float*)d_in[1], (float*)d_out);
}

// Round 5
// 431.404 us; speedup vs baseline: 2.4489x; 2.4489x over previous
//
#include <hip/hip_runtime.h>
#include <cmath>

// ---------------------------------------------------------------------------
// EquivariantCorrectionHead — optimized fused kernel (round 5).
// Half-wave (32 lanes) per element, lane = hidden index w. 16 elements per
// 512-thread block; persistent grid (512 blocks x 16 iterations).
// Weights bf16x2-packed in a 28KB LDS slab (odd strides, conflict-free;
// 2-way half-pair broadcast is free). C222 computed analytically on HOST
// (round-4 sign convention: C = +T/||T||) and passed as kernel args -> SGPRs.
// Per-element scratch: qT/h2 as padded 8-word rows (b128 reads). No barriers
// in the main loop (all deps within one half-wave; DS in-order per wave —
// mechanism exonerated by r1==r3 bit-identical outputs).
// ---------------------------------------------------------------------------

#define DEVINL static __device__ __forceinline__

// packed slab word offsets (g_ws and LDS share layout)
#define PW000 0        // 32 x 69 (68 used) bf16x2 pairs of sym-upper-tri(16)
#define PW110 2208     // 32 x 23 (45 vals) bf16x2
#define PWC   2944     // 32 x 73 (72 used) bf16x2: [w][up*9+v] = (u=2up,2up+1)
#define PW111 5280     // 32 x 23
#define PV110 6016     // 32 x 17 (16 used): [u][vp] = v110[u][2vp,2vp+1]
#define PMR   6560     // 32 x 17: [w][up] = Mr[w][2up,2up+1]
#define SLABW 7104

__device__ __align__(16) float g_ws[SLABW];

struct CPack { float v[32]; };

// C222 nonzero superset (exact O(3) parity selection rule)
static constexpr int CIa[32] = {2,2,2,4,2,4,4,4, 2,0,0, 2,1,1, 2,3,3, 4,0,0, 4,1,1, 4,3,3, 0,0,1,1,3,3};
static constexpr int CJa[32] = {2,2,4,2,4,2,4,4, 0,2,0, 1,2,1, 3,2,3, 0,4,0, 1,4,1, 3,4,3, 1,3,0,3,0,1};
static constexpr int CKa[32] = {2,4,2,2,4,4,2,4, 0,0,2, 1,1,2, 3,3,2, 0,0,4, 1,1,4, 3,3,4, 3,1,3,0,1,0};

__host__ __device__ inline void tri_uv(int p, int n, int& u, int& v) {
  int base = 0;
  for (int x = 0; x < n; x++) {
    int c = n - x;
    if (p < base + c) { u = x; v = x + (p - base); return; }
    base += c;
  }
  u = n - 1; v = n - 1;
}

// ---------------------------------------------------------------------------
// Host: analytic C222 (traceless-symmetric basis), round-4 sign convention.
// ---------------------------------------------------------------------------
static double h_trE3(const double A[3][3], const double B[3][3], const double C[3][3]) {
  double t = 0.0;
  for (int r = 0; r < 3; r++)
    for (int c = 0; c < 3; c++) {
      double ab = 0.0;
      for (int m = 0; m < 3; m++) ab += A[r][m] * B[m][c];
      t += ab * C[c][r];
    }
  return t;
}

static void computeC(CPack& out) {
  const double s2i = 0.7071067811865475244;
  const double s6i = 0.4082482904638630164;
  double E[5][3][3] = {
    {{0, s2i, 0}, {s2i, 0, 0}, {0, 0, 0}},
    {{0, 0, 0}, {0, 0, s2i}, {0, s2i, 0}},
    {{-s6i, 0, 0}, {0, -s6i, 0}, {0, 0, 2.0 * s6i}},
    {{0, 0, s2i}, {0, 0, 0}, {s2i, 0, 0}},
    {{s2i, 0, 0}, {0, -s2i, 0}, {0, 0, 0}}
  };
  double T[125];
  double nrm = 0.0;
  for (int f = 0; f < 125; f++) {
    int i = f / 25, j = (f / 5) % 5, k = f % 5;
    T[f] = h_trE3(E[i], E[j], E[k]) + h_trE3(E[i], E[k], E[j]);
    nrm += T[f] * T[f];
  }
  nrm = std::sqrt(nrm);
  int am = 0; double mx = std::fabs(T[0]);
  for (int q = 1; q < 125; q++) { double v = std::fabs(T[q]); if (v > mx) { mx = v; am = q; } }
  double sgn = (T[am] < 0.0) ? -1.0 : 1.0;
  const double scale = -sgn / nrm;   // round-4 proven convention
  for (int s = 0; s < 32; s++)
    out.v[s] = (float)(scale * T[(CIa[s] * 5 + CJa[s]) * 5 + CKa[s]]);
}

// ---------------------------------------------------------------------------
// bf16 helpers
// ---------------------------------------------------------------------------
DEVINL unsigned short f2bf(float f) {
  unsigned x = __float_as_uint(f);
  return (unsigned short)((x + 0x7fffu + ((x >> 16) & 1u)) >> 16);
}
DEVINL unsigned packbf(float a, float b) {
  return (unsigned)f2bf(a) | ((unsigned)f2bf(b) << 16);
}
DEVINL float bflo(unsigned w) { return __uint_as_float(w << 16); }
DEVINL float bfhi(unsigned w) { return __uint_as_float(w & 0xffff0000u); }

// ---------------------------------------------------------------------------
// Setup kernel: pack weights (symmetrized, constants folded) into g_ws
// ---------------------------------------------------------------------------
__global__ void ech_setup(const float* __restrict__ w000, const float* __restrict__ w110,
                          const float* __restrict__ w011, const float* __restrict__ w101,
                          const float* __restrict__ w111, const float* __restrict__ v010,
                          const float* __restrict__ v100, const float* __restrict__ v110) {
  const float c0   = 1.0f / sqrtf(337.0f);
  const float inv5 = 0.44721359549995794f;
  const float c2   = sqrtf(5.0f / 369.0f);
  const float dm   = sqrtf(5.0f / 3072.0f) * inv5;
  int gid = blockIdx.x * blockDim.x + threadIdx.x;
  int gs  = gridDim.x * blockDim.x;
  unsigned* gsl = (unsigned*)g_ws;

  // w000 sym upper-tri, c0 folded, pairs (2pp,2pp+1), 68 exact
  for (int idx = gid; idx < 32 * 68; idx += gs) {
    int w = idx / 68, pp = idx % 68;
    int u0, v0, u1, v1;
    tri_uv(2 * pp, 16, u0, v0);
    tri_uv(2 * pp + 1, 16, u1, v1);
    float a = c0 * (w000[(u0 * 16 + v0) * 32 + w] + (u0 != v0 ? w000[(v0 * 16 + u0) * 32 + w] : 0.0f));
    float b = c0 * (w000[(u1 * 16 + v1) * 32 + w] + (u1 != v1 ? w000[(v1 * 16 + u1) * 32 + w] : 0.0f));
    gsl[PW000 + w * 69 + pp] = packbf(a, b);
  }
  // w110 sym, c0/sqrt5 folded, 45 vals -> 23 pairs (last hi = 0)
  for (int idx = gid; idx < 32 * 23; idx += gs) {
    int w = idx / 23, pp = idx % 23;
    float a, b = 0.0f;
    int u, v;
    tri_uv(2 * pp, 9, u, v);
    a = c0 * inv5 * (w110[(u * 9 + v) * 32 + w] + (u != v ? w110[(v * 9 + u) * 32 + w] : 0.0f));
    if (2 * pp + 1 < 45) {
      tri_uv(2 * pp + 1, 9, u, v);
      b = c0 * inv5 * (w110[(u * 9 + v) * 32 + w] + (u != v ? w110[(v * 9 + u) * 32 + w] : 0.0f));
    }
    gsl[PW110 + w * 23 + pp] = packbf(a, b);
  }
  // wc: [w][up*9+v] packs scalar-u pair (2up, 2up+1): c2/sqrt5*(w011[u,v,w]+w101[v,u,w])
  for (int idx = gid; idx < 32 * 72; idx += gs) {
    int w = idx / 72, r = idx % 72, up = r / 9, v = r % 9;
    int a0 = 2 * up, a1 = 2 * up + 1;
    float lo = c2 * inv5 * (w011[(a0 * 9 + v) * 32 + w] + w101[(v * 16 + a0) * 32 + w]);
    float hi = c2 * inv5 * (w011[(a1 * 9 + v) * 32 + w] + w101[(v * 16 + a1) * 32 + w]);
    gsl[PWC + w * 73 + r] = packbf(lo, hi);
  }
  // w111 sym, c2 folded, 45 -> 23 pairs
  for (int idx = gid; idx < 32 * 23; idx += gs) {
    int w = idx / 23, pp = idx % 23;
    float a, b = 0.0f;
    int u, v;
    tri_uv(2 * pp, 9, u, v);
    a = c2 * (w111[(u * 9 + v) * 32 + w] + (u != v ? w111[(v * 9 + u) * 32 + w] : 0.0f));
    if (2 * pp + 1 < 45) {
      tri_uv(2 * pp + 1, 9, u, v);
      b = c2 * (w111[(u * 9 + v) * 32 + w] + (u != v ? w111[(v * 9 + u) * 32 + w] : 0.0f));
    }
    gsl[PW111 + w * 23 + pp] = packbf(a, b);
  }
  // v110: [u][vp] = (v110[u][2vp], v110[u][2vp+1])
  for (int idx = gid; idx < 32 * 16; idx += gs) {
    int u = idx / 16, vp = idx % 16;
    gsl[PV110 + u * 17 + vp] = packbf(v110[u * 32 + 2 * vp], v110[u * 32 + 2 * vp + 1]);
  }
  // Mr: [w][up] = d/sqrt5*(v010[u,w]+v100[w,u]) for u = 2up, 2up+1
  for (int idx = gid; idx < 32 * 16; idx += gs) {
    int w = idx / 16, up = idx % 16;
    int u0 = 2 * up, u1 = 2 * up + 1;
    float a = dm * (v010[u0 * 32 + w] + v100[w * 32 + u0]);
    float b = dm * (v010[u1 * 32 + w] + v100[w * 32 + u1]);
    gsl[PMR + w * 17 + up] = packbf(a, b);
  }
}

// ---------------------------------------------------------------------------
// Main fused kernel
// ---------------------------------------------------------------------------
__global__ void __launch_bounds__(512)
ech_main(const float* __restrict__ sc, const float* __restrict__ t2s,
         float* __restrict__ out, int nGroups, CPack C) {
  __shared__ __align__(16) float slab[SLABW];
  __shared__ __align__(16) float scratch[16 * 504];
  __shared__ int pairs9[48];

  const int tid  = threadIdx.x;
  const int lane = tid & 31;
  const int sub  = tid >> 5;

  { // slab load (once per block)
    const float4* srcv = (const float4*)g_ws;
    float4* dstv = (float4*)slab;
    for (int i = tid; i < SLABW / 4; i += 512) dstv[i] = srcv[i];
  }
  if (tid < 45) { int u, v; tri_uv(tid, 9, u, v); pairs9[tid] = u | (v << 4); }
  __syncthreads();

  constexpr int L2R[8] = {0, 1, 2, 4, 24, 26, 35, 38};
  const unsigned* uslab = (const unsigned*)slab;
  const int w = lane;

  float* A   = scratch + sub * 504;  // 360 words: raw(200) -> qT rows(45x8) -> h2 rows(32x8)
  float* tb  = A + 360;              // 48 (45 used): t[9][5]
  float* tt  = A + 408;              // 48 (45 used + pad zeros)
  float* h0b = A + 456;              // 32

  for (int grp = blockIdx.x; grp < nGroups; grp += gridDim.x) {
    const int b = grp * 16 + sub;

    // ---- phase 0: stage raw t2s row (200 f32) ----
    {
      const float4* srcv = (const float4*)(t2s + (size_t)b * 200);
      float4* Av = (float4*)A;
      Av[lane] = srcv[lane];
      if (lane < 18) Av[lane + 32] = srcv[lane + 32];
    }
    float sreg[16];
    {
      const float4* sv = (const float4*)(sc + (size_t)b * 16);
      #pragma unroll
      for (int i4 = 0; i4 < 4; i4++) {
        float4 x = sv[i4];
        sreg[4 * i4 + 0] = x.x; sreg[4 * i4 + 1] = x.y;
        sreg[4 * i4 + 2] = x.z; sreg[4 * i4 + 3] = x.w;
      }
    }

    // ---- phase 1: build t (8 selected rows + kernel-sum row) ----
    #pragma unroll
    for (int it = 0; it < 2; it++) {
      int idx = lane + 32 * it;
      if (idx < 40) {
        int r = idx / 5, c = idx % 5;
        tb[idx] = A[L2R[r] * 5 + c];
      } else if (idx < 45) {
        int i = idx - 40;
        float acc = 0.f;
        for (int k = 0; k < 40; k++) acc += A[k * 5 + i];
        tb[idx] = acc;
      }
    }
    if (lane >= 29) tt[16 + lane] = 0.f;   // tt[45..47] = 0 (w110 pad)

    // ---- phase 2: pairs -> tt + qT rows (overwrites raw) ----
    #pragma unroll
    for (int it = 0; it < 2; it++) {
      int idx = lane + 32 * it;
      if (idx < 45) {
        int pr = pairs9[idx];
        int pu = pr & 15, pv = pr >> 4;
        float tu[5], tv[5];
        #pragma unroll
        for (int i = 0; i < 5; i++) { tu[i] = tb[pu * 5 + i]; tv[i] = tb[pv * 5 + i]; }
        tt[idx] = tu[0]*tv[0] + tu[1]*tv[1] + tu[2]*tv[2] + tu[3]*tv[3] + tu[4]*tv[4];
        float qk[5] = {0, 0, 0, 0, 0};
        #pragma unroll
        for (int s = 0; s < 32; s++)
          qk[CKa[s]] = fmaf(C.v[s], tu[CIa[s]] * tv[CJa[s]], qk[CKa[s]]);
        ((float4*)(A + idx * 8))[0] = make_float4(qk[0], qk[1], qk[2], qk[3]);
        A[idx * 8 + 4] = qk[4];
      }
    }

    // ---- phase 3: h0[w] (packed w000 + w110) ----
    float h0 = 0.f;
    {
      const unsigned* wr = uslab + PW000 + w * 69;
      int p = 0;
      unsigned word = 0;
      #pragma unroll
      for (int u = 0; u < 16; u++) {
        #pragma unroll
        for (int v = u; v < 16; v++) {
          if ((p & 1) == 0) word = wr[p >> 1];
          float wv = (p & 1) ? bfhi(word) : bflo(word);
          h0 = fmaf(wv, sreg[u] * sreg[v], h0);
          p++;
        }
      }
      const unsigned* wr2 = uslab + PW110 + w * 23;
      #pragma unroll
      for (int pp = 0; pp < 23; pp++) {
        unsigned ww = wr2[pp];
        h0 = fmaf(bflo(ww), tt[2 * pp], h0);
        h0 = fmaf(bfhi(ww), tt[2 * pp + 1], h0);  // tt[45]=0 pad
      }
    }
    h0b[w] = h0;

    // ---- phase 4: h2 s-t merged path (packed wc) ----
    float h2[5] = {0, 0, 0, 0, 0};
    {
      const unsigned* wr = uslab + PWC + w * 73;
      float Cvv[9] = {0, 0, 0, 0, 0, 0, 0, 0, 0};
      #pragma unroll
      for (int up = 0; up < 8; up++) {
        float s0 = sreg[2 * up], s1 = sreg[2 * up + 1];
        #pragma unroll
        for (int v = 0; v < 9; v++) {
          unsigned ww = wr[up * 9 + v];
          Cvv[v] = fmaf(bflo(ww), s0, Cvv[v]);
          Cvv[v] = fmaf(bfhi(ww), s1, Cvv[v]);
        }
      }
      #pragma unroll
      for (int v = 0; v < 9; v++) {
        float cv = Cvv[v];
        #pragma unroll
        for (int k = 0; k < 5; k++) h2[k] = fmaf(cv, tb[v * 5 + k], h2[k]);
      }
    }

    // ---- phase 5: h2 += w111 . qT (packed weights, b128 operand rows) ----
    {
      const unsigned* wr = uslab + PW111 + w * 23;
      #pragma unroll
      for (int pp = 0; pp < 23; pp++) {
        unsigned ww = wr[pp];
        float lo = bflo(ww);
        float4 q0 = *(const float4*)(A + 16 * pp);
        float q04 = A[16 * pp + 4];
        h2[0] = fmaf(lo, q0.x, h2[0]); h2[1] = fmaf(lo, q0.y, h2[1]);
        h2[2] = fmaf(lo, q0.z, h2[2]); h2[3] = fmaf(lo, q0.w, h2[3]);
        h2[4] = fmaf(lo, q04, h2[4]);
        if (pp < 22) {
          float hi = bfhi(ww);
          float4 q1 = *(const float4*)(A + 16 * pp + 8);
          float q14 = A[16 * pp + 12];
          h2[0] = fmaf(hi, q1.x, h2[0]); h2[1] = fmaf(hi, q1.y, h2[1]);
          h2[2] = fmaf(hi, q1.z, h2[2]); h2[3] = fmaf(hi, q1.w, h2[3]);
          h2[4] = fmaf(hi, q14, h2[4]);
        }
      }
    }

    // ---- phase 6: h2 rows -> A (overwrite qT; wave in-order) ----
    ((float4*)(A + w * 8))[0] = make_float4(h2[0], h2[1], h2[2], h2[3]);
    A[w * 8 + 4] = h2[4];

    // ---- phase 7: a[j] = sum_v v110[w,v] h2[v,j] (packed pairs) ----
    float a[5] = {0, 0, 0, 0, 0};
    {
      const unsigned* wr = uslab + PV110 + w * 17;
      #pragma unroll
      for (int vp = 0; vp < 16; vp++) {
        unsigned ww = wr[vp];
        float lo = bflo(ww), hi = bfhi(ww);
        float4 r0 = *(const float4*)(A + 16 * vp);
        float r04 = A[16 * vp + 4];
        float4 r1 = *(const float4*)(A + 16 * vp + 8);
        float r14 = A[16 * vp + 12];
        a[0] = fmaf(lo, r0.x, fmaf(hi, r1.x, a[0]));
        a[1] = fmaf(lo, r0.y, fmaf(hi, r1.y, a[1]));
        a[2] = fmaf(lo, r0.z, fmaf(hi, r1.z, a[2]));
        a[3] = fmaf(lo, r0.w, fmaf(hi, r1.w, a[3]));
        a[4] = fmaf(lo, r04,  fmaf(hi, r14,  a[4]));
      }
    }

    // ---- phase 8: g = sum_u Mr[w,u] h0[u] (d/sqrt5 folded) ----
    float g = 0.f;
    {
      const unsigned* wr = uslab + PMR + w * 17;
      #pragma unroll
      for (int up = 0; up < 16; up++) {
        unsigned ww = wr[up];
        g = fmaf(bflo(ww), h0b[2 * up], g);
        g = fmaf(bfhi(ww), h0b[2 * up + 1], g);
      }
    }

    // ---- phase 9: yv = C.(h2 (x) a); z = DCONST*yv + g*h2; reduce; store ----
    float yv[5] = {0, 0, 0, 0, 0};
    #pragma unroll
    for (int s = 0; s < 32; s++)
      yv[CKa[s]] = fmaf(C.v[s], h2[CIa[s]] * a[CJa[s]], yv[CKa[s]]);

    const float DCONST = sqrtf(5.0f / 3072.0f);
    float z[5];
    #pragma unroll
    for (int k = 0; k < 5; k++) z[k] = fmaf(DCONST, yv[k], g * h2[k]);

    #pragma unroll
    for (int k = 0; k < 5; k++) {
      float v = z[k];
      v += __shfl_xor(v, 1);
      v += __shfl_xor(v, 2);
      v += __shfl_xor(v, 4);
      v += __shfl_xor(v, 8);
      v += __shfl_xor(v, 16);
      z[k] = v;
    }
    if (lane < 5) {
      float val = (lane == 0) ? z[0] : (lane == 1) ? z[1] : (lane == 2) ? z[2]
                : (lane == 3) ? z[3] : z[4];
      out[(size_t)b * 5 + lane] = val;
    }
  }
}

// ---------------------------------------------------------------------------
extern "C" void kernel_launch(void* const* d_in, const int* in_sizes, int n_in,
                              void* d_out, int out_size, void* d_ws, size_t ws_size,
                              hipStream_t stream) {
  (void)n_in; (void)out_size; (void)d_ws; (void)ws_size;

  CPack C;
  computeC(C);

  ech_setup<<<64, 256, 0, stream>>>(
      (const float*)d_in[2], (const float*)d_in[3], (const float*)d_in[4],
      (const float*)d_in[5], (const float*)d_in[6], (const float*)d_in[7],
      (const float*)d_in[8], (const float*)d_in[9]);

  const int B = in_sizes[0] / 16;
  const int nGroups = B / 16;
  ech_main<<<512, 512, 0, stream>>>(
      (const float*)d_in[0], (const float*)d_in[1], (float*)d_out, nGroups, C);
}

// Round 7
// 423.871 us; speedup vs baseline: 2.4924x; 1.0178x over previous
//
#include <hip/hip_runtime.h>
#include <cmath>

// ---------------------------------------------------------------------------
// EquivariantCorrectionHead — round 7 (= round 6 + pk2 type fix).
// Half-wave per element (lane = hidden w), 16 elements / 512-thread block,
// persistent grid. All weight streams AND per-element data vectors stored as
// fp16 pairs; every contraction is v_dot2_f32_f16 (2 MAC/inst, no unpack).
// Slab rows use 8*odd-half strides (16B-aligned b128 reads at the bank floor).
// C222 slot values: host analytic (round-4 sign), passed as kernel args->SGPR.
// All cross-phase deps stay within one half-wave (DS in-order per wave,
// mechanism validated r1==r3); one __syncthreads per block at slab load only.
// ---------------------------------------------------------------------------

#define DEVINL static __device__ __forceinline__

typedef _Float16 half2_t __attribute__((ext_vector_type(2)));
typedef _Float16 half8_t __attribute__((ext_vector_type(8)));
union H8 { half8_t v; half2_t p[4]; };

// ---- slab offsets in HALVES (all rows 16B-aligned; stride = 8*odd) ----
#define HW000 0        // 32 x 136 (stride 136 = 8*17): sym-tri(16) pairs, c0 folded
#define HW110 4352     // 32 x 56  (45 used, pads 0):   sym-tri(9), c0/sqrt5
#define HWC   6144     // 32 x 152 (144 used): [v][u],  c2/sqrt5*(w011+w101^T)
#define HW111 11008    // 32 x 56  (45 used, pads 0):   sym-tri(9), c2
#define HV110 12800    // 32 x 40  (32 used)
#define HMR   14080    // 32 x 40  (32 used): d/sqrt5*(v010^T+v100)
#define SLABH 15360

__device__ __align__(16) _Float16 g_wsh[SLABH];

struct CPack { float v[32]; };

// C222 nonzero superset (exact O(3) parity selection rule)
static constexpr int CIa[32] = {2,2,2,4,2,4,4,4, 2,0,0, 2,1,1, 2,3,3, 4,0,0, 4,1,1, 4,3,3, 0,0,1,1,3,3};
static constexpr int CJa[32] = {2,2,4,2,4,2,4,4, 0,2,0, 1,2,1, 3,2,3, 0,4,0, 1,4,1, 3,4,3, 1,3,0,3,0,1};
static constexpr int CKa[32] = {2,4,2,2,4,4,2,4, 0,0,2, 1,1,2, 3,3,2, 0,0,4, 1,1,4, 3,3,4, 3,1,3,0,1,0};

__host__ __device__ inline void tri_uv(int p, int n, int& u, int& v) {
  int base = 0;
  for (int x = 0; x < n; x++) {
    int c = n - x;
    if (p < base + c) { u = x; v = x + (p - base); return; }
    base += c;
  }
  u = n - 1; v = n - 1;
}

// ---- host analytic C222 (round-4 proven sign) ----
static double h_trE3(const double A[3][3], const double B[3][3], const double C[3][3]) {
  double t = 0.0;
  for (int r = 0; r < 3; r++)
    for (int c = 0; c < 3; c++) {
      double ab = 0.0;
      for (int m = 0; m < 3; m++) ab += A[r][m] * B[m][c];
      t += ab * C[c][r];
    }
  return t;
}
static void computeC(CPack& out) {
  const double s2i = 0.7071067811865475244, s6i = 0.4082482904638630164;
  double E[5][3][3] = {
    {{0, s2i, 0}, {s2i, 0, 0}, {0, 0, 0}},
    {{0, 0, 0}, {0, 0, s2i}, {0, s2i, 0}},
    {{-s6i, 0, 0}, {0, -s6i, 0}, {0, 0, 2.0 * s6i}},
    {{0, 0, s2i}, {0, 0, 0}, {s2i, 0, 0}},
    {{s2i, 0, 0}, {0, -s2i, 0}, {0, 0, 0}}
  };
  double T[125], nrm = 0.0;
  for (int f = 0; f < 125; f++) {
    int i = f / 25, j = (f / 5) % 5, k = f % 5;
    T[f] = h_trE3(E[i], E[j], E[k]) + h_trE3(E[i], E[k], E[j]);
    nrm += T[f] * T[f];
  }
  nrm = std::sqrt(nrm);
  int am = 0; double mx = std::fabs(T[0]);
  for (int q = 1; q < 125; q++) { double v = std::fabs(T[q]); if (v > mx) { mx = v; am = q; } }
  const double scale = ((T[am] < 0.0) ? 1.0 : -1.0) / nrm;   // round-4 sign
  for (int s = 0; s < 32; s++)
    out.v[s] = (float)(scale * T[(CIa[s] * 5 + CJa[s]) * 5 + CKa[s]]);
}

// ---- device helpers ----
DEVINL float dot2f(half2_t a, half2_t b, float c) {
#if __has_builtin(__builtin_amdgcn_fdot2)
  return __builtin_amdgcn_fdot2(a, b, c, false);
#else
  return fmaf((float)a[0], (float)b[0], fmaf((float)a[1], (float)b[1], c));
#endif
}
DEVINL half2_t pk2(float a, float b) {
  auto r = __builtin_amdgcn_cvt_pkrtz(a, b);   // __fp16 ext_vector(2)
  half2_t o;
  __builtin_memcpy(&o, &r, sizeof(o));         // same bits, different FE type
  return o;
}

// ---------------------------------------------------------------------------
// Setup: pack fp16 weight slab (symmetrized, constants folded)
// ---------------------------------------------------------------------------
__global__ void ech_setup(const float* __restrict__ w000, const float* __restrict__ w110,
                          const float* __restrict__ w011, const float* __restrict__ w101,
                          const float* __restrict__ w111, const float* __restrict__ v010,
                          const float* __restrict__ v100, const float* __restrict__ v110) {
  const float c0   = 1.0f / sqrtf(337.0f);
  const float inv5 = 0.44721359549995794f;
  const float c2   = sqrtf(5.0f / 369.0f);
  const float dm   = sqrtf(5.0f / 3072.0f) * inv5;
  int gid = blockIdx.x * blockDim.x + threadIdx.x;
  int gs  = gridDim.x * blockDim.x;

  for (int idx = gid; idx < 32 * 136; idx += gs) {        // w000
    int w = idx / 136, p = idx % 136; int u, v; tri_uv(p, 16, u, v);
    float x = c0 * (w000[(u * 16 + v) * 32 + w] + (u != v ? w000[(v * 16 + u) * 32 + w] : 0.0f));
    g_wsh[HW000 + w * 136 + p] = (_Float16)x;
  }
  for (int idx = gid; idx < 32 * 56; idx += gs) {         // w110 (+zero pads)
    int w = idx / 56, p = idx % 56; float x = 0.0f;
    if (p < 45) { int u, v; tri_uv(p, 9, u, v);
      x = c0 * inv5 * (w110[(u * 9 + v) * 32 + w] + (u != v ? w110[(v * 9 + u) * 32 + w] : 0.0f)); }
    g_wsh[HW110 + w * 56 + p] = (_Float16)x;
  }
  for (int idx = gid; idx < 32 * 144; idx += gs) {        // wc: [v][u]
    int w = idx / 144, r = idx % 144, v = r / 16, u = r % 16;
    float x = c2 * inv5 * (w011[(u * 9 + v) * 32 + w] + w101[(v * 16 + u) * 32 + w]);
    g_wsh[HWC + w * 152 + v * 16 + u] = (_Float16)x;
  }
  for (int idx = gid; idx < 32 * 56; idx += gs) {         // w111 (+zero pads)
    int w = idx / 56, p = idx % 56; float x = 0.0f;
    if (p < 45) { int u, v; tri_uv(p, 9, u, v);
      x = c2 * (w111[(u * 9 + v) * 32 + w] + (u != v ? w111[(v * 9 + u) * 32 + w] : 0.0f)); }
    g_wsh[HW111 + w * 56 + p] = (_Float16)x;
  }
  for (int idx = gid; idx < 1024; idx += gs) {            // v110 rows
    int u = idx / 32, v = idx % 32;
    g_wsh[HV110 + u * 40 + v] = (_Float16)v110[u * 32 + v];
  }
  for (int idx = gid; idx < 1024; idx += gs) {            // Mr
    int w = idx / 32, u = idx % 32;
    g_wsh[HMR + w * 40 + u] = (_Float16)(dm * (v010[u * 32 + w] + v100[w * 32 + u]));
  }
}

// ---------------------------------------------------------------------------
// Main fused kernel
// ---------------------------------------------------------------------------
__global__ void __launch_bounds__(512)
ech_main(const float* __restrict__ sc, const float* __restrict__ t2s,
         float* __restrict__ out, int nGroups, CPack C) {
  __shared__ __align__(16) _Float16 slabh[SLABH];
  __shared__ __align__(16) float scr[16 * 424];
  __shared__ int pairs9[48];
  __shared__ int sspair[68];

  const int tid  = threadIdx.x;
  const int lane = tid & 31;
  const int sub  = tid >> 5;
  const int w    = lane;

  for (int i = tid; i < SLABH / 8; i += 512)
    ((float4*)slabh)[i] = ((const float4*)g_wsh)[i];
  if (tid < 45) { int u, v; tri_uv(tid, 9, u, v); pairs9[tid] = u | (v << 4); }
  if (tid < 68) {
    int u0, v0, u1, v1;
    tri_uv(2 * tid, 16, u0, v0);
    tri_uv(2 * tid + 1, 16, u1, v1);
    sspair[tid] = u0 | (v0 << 4) | (u1 << 8) | (v1 << 12);
  }
  __syncthreads();

  constexpr int L2R[8] = {0, 1, 2, 4, 24, 26, 35, 38};

  // per-element scratch layout (words): see offsets below (all 16B-aligned)
  float*     E    = scr + sub * 424;
  float*     Araw = E;                          // 200 words (overlaid by qh/h2h)
  _Float16*  qhh  = (_Float16*)E;               // [5][48] halves  (words 0..119)
  _Float16*  h2hh = (_Float16*)(E + 120);       // [5][32] halves  (words 120..199)
  float*     tb   = E + 200;                    // 45 f32 (t rows 9x5)
  _Float16*  sshh = (_Float16*)(E + 248);       // 136 halves (68 pairs)
  _Float16*  tthh = (_Float16*)(E + 316);       // 48 halves (45 + pads)
  _Float16*  thh  = (_Float16*)(E + 340);       // [5][16] halves (t transposed)
  _Float16*  h0hh = (_Float16*)(E + 380);       // 32 halves
  float*     sL   = E + 396;                    // 16 f32

  for (int grp = blockIdx.x; grp < nGroups; grp += gridDim.x) {
    const int b = grp * 16 + sub;

    // ---- phase 0: stage raw t2s (200 f32) + scalars ----
    {
      const float4* src = (const float4*)(t2s + (size_t)b * 200);
      float4* Av = (float4*)Araw;
      Av[lane] = src[lane];
      if (lane < 18) Av[lane + 32] = src[lane + 32];
    }
    float sreg[16];
    {
      const float4* sv = (const float4*)(sc + (size_t)b * 16);
      #pragma unroll
      for (int i4 = 0; i4 < 4; i4++) {
        float4 x = sv[i4];
        sreg[4 * i4 + 0] = x.x; sreg[4 * i4 + 1] = x.y;
        sreg[4 * i4 + 2] = x.z; sreg[4 * i4 + 3] = x.w;
      }
      if (lane < 4) ((float4*)sL)[lane] = sv[lane];
    }

    // ---- phase 1: build t rows (fp32 tb + fp16 th transposed) ----
    #pragma unroll
    for (int it = 0; it < 2; it++) {
      int idx = lane + 32 * it;
      if (idx < 40) {
        int r = idx / 5, c = idx % 5;
        float val = Araw[L2R[r] * 5 + c];
        tb[idx] = val;
        thh[c * 16 + r] = (_Float16)val;
      }
    }
    { // kernel-sum row: 25 lanes partial + width-32 shfl gather
      int l25 = lane % 25;
      int c2 = l25 / 5, j2 = l25 % 5;
      float acc = 0.f;
      #pragma unroll
      for (int rr = 0; rr < 8; rr++) acc += Araw[(j2 + 5 * rr) * 5 + c2];
      float tot = __shfl(acc, 5 * c2 + 0, 32) + __shfl(acc, 5 * c2 + 1, 32)
                + __shfl(acc, 5 * c2 + 2, 32) + __shfl(acc, 5 * c2 + 3, 32)
                + __shfl(acc, 5 * c2 + 4, 32);
      if (lane < 25 && j2 == 0) { tb[40 + c2] = tot; thh[c2 * 16 + 8] = (_Float16)tot; }
    }
    // ---- zero all fp16 pads (regions overlay poisoned/raw data) ----
    if (lane < 23) {
      if (lane < 15)      qhh[(lane / 3) * 48 + 45 + lane % 3] = (_Float16)0.f;
      else if (lane < 18) tthh[45 + (lane - 15)] = (_Float16)0.f;
      else                thh[(lane - 18) * 16 + 9] = (_Float16)0.f;
    }

    // ---- phase 2: pairs -> tt (fp16) + qT (fp16) ----
    #pragma unroll
    for (int it = 0; it < 2; it++) {
      int idx = lane + 32 * it;
      if (idx < 45) {
        int pr = pairs9[idx];
        int pu = pr & 15, pv = pr >> 4;
        float tu[5], tv[5];
        #pragma unroll
        for (int i = 0; i < 5; i++) { tu[i] = tb[pu * 5 + i]; tv[i] = tb[pv * 5 + i]; }
        float tt = tu[0]*tv[0] + tu[1]*tv[1] + tu[2]*tv[2] + tu[3]*tv[3] + tu[4]*tv[4];
        tthh[idx] = (_Float16)tt;
        float qk[5] = {0, 0, 0, 0, 0};
        #pragma unroll
        for (int s = 0; s < 32; s++)
          qk[CKa[s]] = fmaf(C.v[s], tu[CIa[s]] * tv[CJa[s]], qk[CKa[s]]);
        #pragma unroll
        for (int k = 0; k < 5; k++) qhh[k * 48 + idx] = (_Float16)qk[k];
      }
    }

    // ---- phase 3a: ss pair products (fp16) ----
    #pragma unroll
    for (int ii = 0; ii < 3; ii++) {
      int slot = lane + 32 * ii;
      if (slot < 68) {
        int t = sspair[slot];
        int u0 = t & 15, v0 = (t >> 4) & 15, u1 = (t >> 8) & 15, v1 = (t >> 12) & 15;
        *(half2_t*)(sshh + 2 * slot) = pk2(sL[u0] * sL[v0], sL[u1] * sL[v1]);
      }
    }

    // ---- phase 3b: h0[w] = W000.ss + W110.tt (dot2 streams) ----
    float h0 = 0.f;
    {
      const _Float16* wr = slabh + HW000 + w * 136;
      #pragma unroll
      for (int i = 0; i < 17; i++) {
        H8 a, d;
        a.v = *(const half8_t*)(wr + 8 * i);
        d.v = *(const half8_t*)(sshh + 8 * i);
        h0 = dot2f(a.p[0], d.p[0], h0); h0 = dot2f(a.p[1], d.p[1], h0);
        h0 = dot2f(a.p[2], d.p[2], h0); h0 = dot2f(a.p[3], d.p[3], h0);
      }
      const _Float16* wr2 = slabh + HW110 + w * 56;
      #pragma unroll
      for (int i = 0; i < 6; i++) {
        H8 a, d;
        a.v = *(const half8_t*)(wr2 + 8 * i);
        d.v = *(const half8_t*)(tthh + 8 * i);
        h0 = dot2f(a.p[0], d.p[0], h0); h0 = dot2f(a.p[1], d.p[1], h0);
        h0 = dot2f(a.p[2], d.p[2], h0); h0 = dot2f(a.p[3], d.p[3], h0);
      }
    }
    h0hh[w] = (_Float16)h0;

    // ---- phase 4: Cvv = WC.s ; h2 = Cvv.t ----
    half2_t sh[8];
    #pragma unroll
    for (int i = 0; i < 8; i++) sh[i] = pk2(sreg[2 * i], sreg[2 * i + 1]);
    float Cvv[9];
    {
      const _Float16* wr = slabh + HWC + w * 152;
      #pragma unroll
      for (int v = 0; v < 9; v++) {
        H8 a0, a1;
        a0.v = *(const half8_t*)(wr + v * 16);
        a1.v = *(const half8_t*)(wr + v * 16 + 8);
        float acc = dot2f(a0.p[0], sh[0], 0.f);
        acc = dot2f(a0.p[1], sh[1], acc); acc = dot2f(a0.p[2], sh[2], acc);
        acc = dot2f(a0.p[3], sh[3], acc); acc = dot2f(a1.p[0], sh[4], acc);
        acc = dot2f(a1.p[1], sh[5], acc); acc = dot2f(a1.p[2], sh[6], acc);
        acc = dot2f(a1.p[3], sh[7], acc);
        Cvv[v] = acc;
      }
    }
    half2_t cpk[5] = { pk2(Cvv[0], Cvv[1]), pk2(Cvv[2], Cvv[3]),
                       pk2(Cvv[4], Cvv[5]), pk2(Cvv[6], Cvv[7]), pk2(Cvv[8], 0.f) };
    float h2r[5];
    #pragma unroll
    for (int k = 0; k < 5; k++) {
      H8 d; d.v = *(const half8_t*)(thh + k * 16);
      half2_t d4 = *(const half2_t*)(thh + k * 16 + 8);
      float acc = dot2f(cpk[0], d.p[0], 0.f);
      acc = dot2f(cpk[1], d.p[1], acc);
      acc = dot2f(cpk[2], d.p[2], acc);
      acc = dot2f(cpk[3], d.p[3], acc);
      acc = dot2f(cpk[4], d4, acc);
      h2r[k] = acc;
    }

    // ---- phase 5: h2 += W111 . qT ----
    {
      H8 wk[6];
      const _Float16* wr = slabh + HW111 + w * 56;
      #pragma unroll
      for (int i = 0; i < 6; i++) wk[i].v = *(const half8_t*)(wr + 8 * i);
      #pragma unroll
      for (int k = 0; k < 5; k++) {
        const _Float16* qr = qhh + k * 48;
        float acc = h2r[k];
        #pragma unroll
        for (int i = 0; i < 6; i++) {
          H8 d; d.v = *(const half8_t*)(qr + 8 * i);
          acc = dot2f(wk[i].p[0], d.p[0], acc); acc = dot2f(wk[i].p[1], d.p[1], acc);
          acc = dot2f(wk[i].p[2], d.p[2], acc); acc = dot2f(wk[i].p[3], d.p[3], acc);
        }
        h2r[k] = acc;
      }
    }

    // ---- phase 6: h2 -> fp16 rows [j][32] ----
    #pragma unroll
    for (int k = 0; k < 5; k++) h2hh[k * 32 + w] = (_Float16)h2r[k];

    // ---- phase 7: a[j] = V110[w,:] . h2[:,j] ----
    float a5[5];
    {
      H8 wk[4];
      const _Float16* wr = slabh + HV110 + w * 40;
      #pragma unroll
      for (int i = 0; i < 4; i++) wk[i].v = *(const half8_t*)(wr + 8 * i);
      #pragma unroll
      for (int j = 0; j < 5; j++) {
        const _Float16* hr = h2hh + j * 32;
        float acc = 0.f;
        #pragma unroll
        for (int i = 0; i < 4; i++) {
          H8 d; d.v = *(const half8_t*)(hr + 8 * i);
          acc = dot2f(wk[i].p[0], d.p[0], acc); acc = dot2f(wk[i].p[1], d.p[1], acc);
          acc = dot2f(wk[i].p[2], d.p[2], acc); acc = dot2f(wk[i].p[3], d.p[3], acc);
        }
        a5[j] = acc;
      }
    }

    // ---- phase 8: g = Mr[w,:] . h0 ----
    float g = 0.f;
    {
      const _Float16* wr = slabh + HMR + w * 40;
      #pragma unroll
      for (int i = 0; i < 4; i++) {
        H8 a, d;
        a.v = *(const half8_t*)(wr + 8 * i);
        d.v = *(const half8_t*)(h0hh + 8 * i);
        g = dot2f(a.p[0], d.p[0], g); g = dot2f(a.p[1], d.p[1], g);
        g = dot2f(a.p[2], d.p[2], g); g = dot2f(a.p[3], d.p[3], g);
      }
    }

    // ---- phase 9: yv = C.(h2 (x) a); z = DCONST*yv + g*h2; reduce; store ----
    float yv[5] = {0, 0, 0, 0, 0};
    #pragma unroll
    for (int s = 0; s < 32; s++)
      yv[CKa[s]] = fmaf(C.v[s], h2r[CIa[s]] * a5[CJa[s]], yv[CKa[s]]);

    const float DCONST = sqrtf(5.0f / 3072.0f);
    float z[5];
    #pragma unroll
    for (int k = 0; k < 5; k++) z[k] = fmaf(DCONST, yv[k], g * h2r[k]);

    #pragma unroll
    for (int k = 0; k < 5; k++) {
      float v = z[k];
      v += __shfl_xor(v, 1);
      v += __shfl_xor(v, 2);
      v += __shfl_xor(v, 4);
      v += __shfl_xor(v, 8);
      v += __shfl_xor(v, 16);
      z[k] = v;
    }
    if (lane < 5) {
      float val = (lane == 0) ? z[0] : (lane == 1) ? z[1] : (lane == 2) ? z[2]
                : (lane == 3) ? z[3] : z[4];
      out[(size_t)b * 5 + lane] = val;
    }
  }
}

// ---------------------------------------------------------------------------
extern "C" void kernel_launch(void* const* d_in, const int* in_sizes, int n_in,
                              void* d_out, int out_size, void* d_ws, size_t ws_size,
                              hipStream_t stream) {
  (void)n_in; (void)out_size; (void)d_ws; (void)ws_size;

  CPack C;
  computeC(C);

  ech_setup<<<64, 256, 0, stream>>>(
      (const float*)d_in[2], (const float*)d_in[3], (const float*)d_in[4],
      (const float*)d_in[5], (const float*)d_in[6], (const float*)d_in[7],
      (const float*)d_in[8], (const float*)d_in[9]);

  const int B = in_sizes[0] / 16;
  const int nGroups = B / 16;
  ech_main<<<512, 512, 0, stream>>>(
      (const float*)d_in[0], (const float*)d_in[1], (float*)d_out, nGroups, C);
}